// Round 10
// baseline (140.025 us; speedup 1.0000x reference)
//
#include <hip/hip_runtime.h>
#include <hip/hip_bf16.h>

#define HID 512
#define BATCH 2048

typedef __bf16 bf16x8 __attribute__((ext_vector_type(8)));
typedef float f32x4 __attribute__((ext_vector_type(4)));
typedef float f32x16 __attribute__((ext_vector_type(16)));
typedef __hip_bfloat16 bf16;

__device__ inline unsigned short f2bf(float x) {
    bf16 h = __float2bfloat16(x);
    return __builtin_bit_cast(unsigned short, h);
}
__device__ inline float bf2f(unsigned short u) {
    return __bfloat162float(__builtin_bit_cast(bf16, u));
}

__device__ inline void gload16(const void* g, void* l) {
    __builtin_amdgcn_global_load_lds((const __attribute__((address_space(1))) void*)g,
                                     (__attribute__((address_space(3))) void*)l, 16, 0, 0);
}

// ---------------- merged: weight fp32 -> hi/lo bf16 split  +  input projection ----------------
struct CvtArgs { const float* src[8]; };

__global__ void k_prep(CvtArgs a, unsigned short* __restrict__ hi, unsigned short* __restrict__ lo,
                       const float* __restrict__ V, const float* __restrict__ t,
                       const float* __restrict__ ipw, const float* __restrict__ ipb,
                       unsigned short* __restrict__ hhi, unsigned short* __restrict__ hlo) {
    const int bid = blockIdx.x;
    if (bid < 3584) {   // cvt part: 3,670,016 elems / 4
        int idx4 = (bid * 256 + threadIdx.x) << 2;
        int seg, off;
        if (idx4 < 2097152) { seg = idx4 >> 20; off = idx4 & 1048575; }
        else { int r = idx4 - 2097152; seg = 2 + (r >> 18); off = r & 262143; }
        f32x4 w = *(const f32x4*)(a.src[seg] + off);
        ushort4 h, l;
        h.x = f2bf(w[0]); h.y = f2bf(w[1]); h.z = f2bf(w[2]); h.w = f2bf(w[3]);
        l.x = f2bf(w[0] - bf2f(h.x)); l.y = f2bf(w[1] - bf2f(h.y));
        l.z = f2bf(w[2] - bf2f(h.z)); l.w = f2bf(w[3] - bf2f(h.w));
        *(ushort4*)(hi + idx4) = h;
        *(ushort4*)(lo + idx4) = l;
    } else {            // h0 part: B*HID/4 elems
        int idx = (bid - 3584) * 256 + threadIdx.x;
        int b = idx >> 7, j4 = (idx & 127) << 2;
        float vv = V[b], tt = t[b];
        f32x4 w0 = *(const f32x4*)(ipw + 2 * j4);
        f32x4 w1 = *(const f32x4*)(ipw + 2 * j4 + 4);
        f32x4 bb = *(const f32x4*)(ipb + j4);
        float x[4] = { w0[0] * vv + w0[1] * tt + bb[0], w0[2] * vv + w0[3] * tt + bb[1],
                       w1[0] * vv + w1[1] * tt + bb[2], w1[2] * vv + w1[3] * tt + bb[3] };
        ushort4 h, l;
        h.x = f2bf(x[0]); h.y = f2bf(x[1]); h.z = f2bf(x[2]); h.w = f2bf(x[3]);
        l.x = f2bf(x[0] - bf2f(h.x)); l.y = f2bf(x[1] - bf2f(h.y));
        l.z = f2bf(x[2] - bf2f(h.z)); l.w = f2bf(x[3] - bf2f(h.w));
        size_t o = (size_t)b * HID + j4;
        *(ushort4*)(hhi + o) = h;
        *(ushort4*)(hlo + o) = l;
    }
}

// ---------------- fused sLSTM GEMM: gates + activation in epilogue ----------------
// Block: 32 m-rows x (128 j-cols x 3 segments i/g/o), K=512, 4 waves.
// Wave w owns frag-cols rb = {w, 4+w, 8+w} -> thread holds i,g,o for SAME (row, j).
// LDS: 3 bufs x 26 chunks x 1KB. Chunk 0=Ah, 1=Al, 2+2*rb+f = W(rb, f=hi/lo).
// W-row(rb) = {0,1024,1536}[rb>>2] + jb + (rb&3)*32.
// Stage split: w0 chunks 0-5 (6), w1 6-13 (8), w2 14-21 (8), w3 22-25 (4).
__global__ __launch_bounds__(256) void k_gemm_s(
    const bf16* __restrict__ Ahi, const bf16* __restrict__ Alo,
    const bf16* __restrict__ Whi, const bf16* __restrict__ Wlo,   // [2048][512] layer weight
    const float* __restrict__ bp,                                  // [2048] bias
    unsigned short* __restrict__ hhi, unsigned short* __restrict__ hlo)
{
    __shared__ __align__(16) bf16 lds[39936];   // 3 x 13312 elems (26KB per buffer)
    const int tid = threadIdx.x, w = tid >> 6, lane = tid & 63;

    const int bid = blockIdx.x;                 // 256 blocks: 8 XCD x 32 slots
    const int xcd = bid & 7, slot = bid >> 3;   // slot 0..31
    const int m0 = (xcd * 8 + (slot >> 2)) * 32;
    const int jb = (slot & 3) * 128;

    const int cbase = (w == 0) ? 0 : (w == 1) ? 6 : (w == 2) ? 14 : 22;
    const int cnt   = (w == 0) ? 6 : (w == 3) ? 4 : 8;
    const int rowoff = (lane & 31);
    const int koff = (lane >> 5) << 3;

    auto chunk_src = [&](int c) -> const bf16* {
        if (c == 0) return Ahi + (size_t)(m0 + rowoff) * HID + koff;
        if (c == 1) return Alo + (size_t)(m0 + rowoff) * HID + koff;
        int rb = (c - 2) >> 1, f = (c - 2) & 1;
        int sb = (rb >> 2) == 0 ? 0 : ((rb >> 2) == 1 ? 1024 : 1536);
        const bf16* base = f ? Wlo : Whi;
        return base + (size_t)(sb + jb + ((rb & 3) << 5) + rowoff) * HID + koff;
    };
    const bf16* p0 = chunk_src(cbase + 0);
    const bf16* p1 = chunk_src(cbase + 1);
    const bf16* p2 = chunk_src(cbase + 2);
    const bf16* p3 = chunk_src(cbase + 3);
    const bf16* p4 = chunk_src(cnt > 4 ? cbase + 4 : cbase);
    const bf16* p5 = chunk_src(cnt > 5 ? cbase + 5 : cbase);
    const bf16* p6 = chunk_src(cnt > 6 ? cbase + 6 : cbase);
    const bf16* p7 = chunk_src(cnt > 7 ? cbase + 7 : cbase);
    bf16* const dbase = lds + (cbase << 9) + (lane << 3);

    auto STAGE = [&](int t) {
        bf16* d = dbase + (t % 3) * 13312;
        const int ko = t << 4;
        gload16(p0 + ko, d);
        gload16(p1 + ko, d + 512);
        gload16(p2 + ko, d + 1024);
        gload16(p3 + ko, d + 1536);
        if (cnt > 4) gload16(p4 + ko, d + 2048);
        if (cnt > 5) gload16(p5 + ko, d + 2560);
        if (cnt > 6) gload16(p6 + ko, d + 3072);
        if (cnt > 7) gload16(p7 + ko, d + 3584);
    };

    const int la = lane << 3;
    f32x16 accI = {}, accG = {}, accO = {};
    const int whc0 = (2 + (0 * 4 + w) * 2) << 9, wlc0 = whc0 + 512;
    const int whc1 = (2 + (1 * 4 + w) * 2) << 9, wlc1 = whc1 + 512;
    const int whc2 = (2 + (2 * 4 + w) * 2) << 9, wlc2 = whc2 + 512;

    STAGE(0);
    STAGE(1);
    for (int t = 0; t < 32; ++t) {
        if (t < 31) {
            if (w == 0)      asm volatile("s_waitcnt vmcnt(6) lgkmcnt(0)\n\ts_barrier" ::: "memory");
            else if (w == 3) asm volatile("s_waitcnt vmcnt(4) lgkmcnt(0)\n\ts_barrier" ::: "memory");
            else             asm volatile("s_waitcnt vmcnt(8) lgkmcnt(0)\n\ts_barrier" ::: "memory");
        } else {
            asm volatile("s_waitcnt vmcnt(0) lgkmcnt(0)\n\ts_barrier" ::: "memory");
        }
        if (t < 30) STAGE(t + 2);
        const bf16* lb = lds + (t % 3) * 13312;
        bf16x8 ah = *(const bf16x8*)(lb + la);
        bf16x8 al = *(const bf16x8*)(lb + 512 + la);
        bf16x8 wh0 = *(const bf16x8*)(lb + whc0 + la);
        bf16x8 wl0 = *(const bf16x8*)(lb + wlc0 + la);
        bf16x8 wh1 = *(const bf16x8*)(lb + whc1 + la);
        bf16x8 wl1 = *(const bf16x8*)(lb + wlc1 + la);
        bf16x8 wh2 = *(const bf16x8*)(lb + whc2 + la);
        bf16x8 wl2 = *(const bf16x8*)(lb + wlc2 + la);
        accI = __builtin_amdgcn_mfma_f32_32x32x16_bf16(ah, wh0, accI, 0, 0, 0);
        accG = __builtin_amdgcn_mfma_f32_32x32x16_bf16(ah, wh1, accG, 0, 0, 0);
        accO = __builtin_amdgcn_mfma_f32_32x32x16_bf16(ah, wh2, accO, 0, 0, 0);
        accI = __builtin_amdgcn_mfma_f32_32x32x16_bf16(al, wh0, accI, 0, 0, 0);
        accG = __builtin_amdgcn_mfma_f32_32x32x16_bf16(al, wh1, accG, 0, 0, 0);
        accO = __builtin_amdgcn_mfma_f32_32x32x16_bf16(al, wh2, accO, 0, 0, 0);
        accI = __builtin_amdgcn_mfma_f32_32x32x16_bf16(ah, wl0, accI, 0, 0, 0);
        accG = __builtin_amdgcn_mfma_f32_32x32x16_bf16(ah, wl1, accG, 0, 0, 0);
        accO = __builtin_amdgcn_mfma_f32_32x32x16_bf16(ah, wl2, accO, 0, 0, 0);
    }

    // epilogue: activation, thread-local (i,g,o triple per slot)
    const int col = jb + (w << 5) + (lane & 31);
    const float bi = bp[col], bg = bp[1024 + col], bo = bp[1536 + col];
    const int rb4 = (lane >> 5) << 2;
#pragma unroll
    for (int rr = 0; rr < 16; ++rr) {
        int row = m0 + (rr & 3) + ((rr >> 2) << 3) + rb4;
        float x = tanhf(expf(accI[rr] + bi) * tanhf(accG[rr] + bg)) /
                  (1.f + expf(-(accO[rr] + bo)));
        unsigned short h = f2bf(x);
        size_t p = (size_t)row * HID + col;
        hhi[p] = h;
        hlo[p] = f2bf(x - bf2f(h));
    }
}

// ---------------- mLSTM qkv GEMM (native-K, no split-K, 3-deep counted-vmcnt) ----------------
// C[2048][1536] = Ah*Wh + Al*Wh + Ah*Wl over K=512.  Block 128x128, 4 waves, BK=16, 32 steps.
__global__ __launch_bounds__(256, 2) void k_gemm_m(
    const bf16* __restrict__ Ahi, const bf16* __restrict__ Alo,
    const bf16* __restrict__ Wh0, const bf16* __restrict__ Wh1, const bf16* __restrict__ Wh2,
    const bf16* __restrict__ Wl0, const bf16* __restrict__ Wl1, const bf16* __restrict__ Wl2,
    float* __restrict__ C)
{
    __shared__ __align__(16) bf16 lds[3][8192];   // 48 KB
    const int tid = threadIdx.x, w = tid >> 6, lane = tid & 63;

    const int bid = blockIdx.x;                   // 192 blocks: 8 XCD x 24 slots
    const int xcd = bid & 7, slot = bid >> 3;     // slot 0..23
    const int m0 = (xcd * 2 + slot / 12) * 128;
    const int n0 = (slot % 12) * 128;
    const int nseg = n0 >> 9, nloc = n0 & 511;
    const bf16* Wh = nseg == 0 ? Wh0 : (nseg == 1 ? Wh1 : Wh2);
    const bf16* Wl = nseg == 0 ? Wl0 : (nseg == 1 ? Wl1 : Wl2);

    const bf16* msrc = (w == 0) ? Ahi : (w == 1) ? Alo : (w == 2) ? Wh : Wl;
    const int rowbase = (w < 2) ? m0 : nloc;
    const size_t srow = (size_t)(rowbase + (lane & 31)) * HID + ((lane >> 5) << 3);

    auto STAGE = [&](int t) {
        bf16* db = &lds[t % 3][0] + (w << 11) + (lane << 3);
        const bf16* gp = msrc + srow + (t << 4);
#pragma unroll
        for (int p = 0; p < 4; ++p)
            gload16(gp + (size_t)(p << 5) * HID, db + (p << 9));
    };

    const int wm = w >> 1, wn = w & 1;
    const int la = lane << 3;
    f32x16 acc00 = {}, acc01 = {}, acc10 = {}, acc11 = {};

    STAGE(0);
    STAGE(1);
    for (int t = 0; t < 32; ++t) {
        if (t < 31)
            asm volatile("s_waitcnt vmcnt(4) lgkmcnt(0)\n\ts_barrier" ::: "memory");
        else
            asm volatile("s_waitcnt vmcnt(0) lgkmcnt(0)\n\ts_barrier" ::: "memory");
        if (t < 30) STAGE(t + 2);
        const bf16* lb = &lds[t % 3][0];
        bf16x8 ah0 = *(const bf16x8*)(lb + ((2 * wm    ) << 9) + la);
        bf16x8 ah1 = *(const bf16x8*)(lb + ((2 * wm + 1) << 9) + la);
        bf16x8 al0 = *(const bf16x8*)(lb + ((4 + 2 * wm    ) << 9) + la);
        bf16x8 al1 = *(const bf16x8*)(lb + ((4 + 2 * wm + 1) << 9) + la);
        bf16x8 wh0 = *(const bf16x8*)(lb + ((8 + 2 * wn    ) << 9) + la);
        bf16x8 wh1 = *(const bf16x8*)(lb + ((8 + 2 * wn + 1) << 9) + la);
        bf16x8 wl0 = *(const bf16x8*)(lb + ((12 + 2 * wn    ) << 9) + la);
        bf16x8 wl1 = *(const bf16x8*)(lb + ((12 + 2 * wn + 1) << 9) + la);
        acc00 = __builtin_amdgcn_mfma_f32_32x32x16_bf16(ah0, wh0, acc00, 0, 0, 0);
        acc01 = __builtin_amdgcn_mfma_f32_32x32x16_bf16(ah0, wh1, acc01, 0, 0, 0);
        acc10 = __builtin_amdgcn_mfma_f32_32x32x16_bf16(ah1, wh0, acc10, 0, 0, 0);
        acc11 = __builtin_amdgcn_mfma_f32_32x32x16_bf16(ah1, wh1, acc11, 0, 0, 0);
        acc00 = __builtin_amdgcn_mfma_f32_32x32x16_bf16(al0, wh0, acc00, 0, 0, 0);
        acc01 = __builtin_amdgcn_mfma_f32_32x32x16_bf16(al0, wh1, acc01, 0, 0, 0);
        acc10 = __builtin_amdgcn_mfma_f32_32x32x16_bf16(al1, wh0, acc10, 0, 0, 0);
        acc11 = __builtin_amdgcn_mfma_f32_32x32x16_bf16(al1, wh1, acc11, 0, 0, 0);
        acc00 = __builtin_amdgcn_mfma_f32_32x32x16_bf16(ah0, wl0, acc00, 0, 0, 0);
        acc01 = __builtin_amdgcn_mfma_f32_32x32x16_bf16(ah0, wl1, acc01, 0, 0, 0);
        acc10 = __builtin_amdgcn_mfma_f32_32x32x16_bf16(ah1, wl0, acc10, 0, 0, 0);
        acc11 = __builtin_amdgcn_mfma_f32_32x32x16_bf16(ah1, wl1, acc11, 0, 0, 0);
    }

    const f32x16* accs[2][2] = { { &acc00, &acc01 }, { &acc10, &acc11 } };
#pragma unroll
    for (int fi = 0; fi < 2; ++fi)
#pragma unroll
        for (int fj = 0; fj < 2; ++fj) {
            const f32x16& ac = *accs[fi][fj];
            const int col = n0 + ((2 * wn + fj) << 5) + (lane & 31);
            const int rbase = m0 + ((2 * wm + fi) << 5) + ((lane >> 5) << 2);
#pragma unroll
            for (int rr = 0; rr < 16; ++rr) {
                int row = rbase + (rr & 3) + ((rr >> 2) << 3);
                C[(size_t)row * 1536 + col] = ac[rr];
            }
        }
}

// ---------------- mLSTM head math + layernorm (+optional fused final projection) ----------------
__global__ __launch_bounds__(512) void k_mlstm(
    const float* __restrict__ g0,
    const float* __restrict__ bq, const float* __restrict__ bk, const float* __restrict__ bv,
    const bf16* __restrict__ hinh, const bf16* __restrict__ hinl,
    const float* __restrict__ igw, const float* __restrict__ igb,
    const float* __restrict__ lng, const float* __restrict__ lnb,
    unsigned short* __restrict__ outh, unsigned short* __restrict__ outl,
    const float* __restrict__ opw, const float* __restrict__ opb, float* __restrict__ out)
{
    int b = blockIdx.x;
    int tid = threadIdx.x, head = tid >> 6, lane = tid & 63;

    const bf16*  hh = hinh + (size_t)b * HID;
    const bf16*  hl = hinl + (size_t)b * HID;
    const float* wrow = igw + head * HID;
    float s = 0.f;
#pragma unroll
    for (int k = 0; k < 8; ++k) {
        int p = lane + 64 * k;
        s += wrow[p] * (__bfloat162float(hh[p]) + __bfloat162float(hl[p]));
    }
#pragma unroll
    for (int off = 32; off; off >>= 1) s += __shfl_xor(s, off);
    float ig = expf(s + igb[head]);

    const float* r0 = g0 + (size_t)b * 1536;
    float q  = r0[tid] + bq[tid];
    float kk = r0[512 + tid] + bk[tid];
    float v  = r0[1024 + tid] + bv[tid];
    float kq = kk * q, vq = v * q;
#pragma unroll
    for (int off = 32; off; off >>= 1) { kq += __shfl_xor(kq, off); vq += __shfl_xor(vq, off); }
    float den = ig * (vq + 1.0f) + 1e-6f;
    float hv  = v * (ig * kq) / den;

    __shared__ float red[16];
    __shared__ float red2[8];
    float s1 = hv, s2 = hv * hv;
#pragma unroll
    for (int off = 32; off; off >>= 1) { s1 += __shfl_xor(s1, off); s2 += __shfl_xor(s2, off); }
    if (lane == 0) { red[head] = s1; red[8 + head] = s2; }
    __syncthreads();
    float t1 = 0.f, t2 = 0.f;
#pragma unroll
    for (int h2 = 0; h2 < 8; ++h2) { t1 += red[h2]; t2 += red[8 + h2]; }
    float mu  = t1 * (1.f / 512.f);
    float var = t2 * (1.f / 512.f) - mu * mu;
    float o = (hv - mu) * rsqrtf(var + 1e-5f) * lng[tid] + lnb[tid];

    if (out) {   // fused final projection (layer 3)
        float po = o * opw[tid];
#pragma unroll
        for (int off = 32; off; off >>= 1) po += __shfl_xor(po, off);
        if (lane == 0) red2[head] = po;
        __syncthreads();
        if (tid == 0) {
            float tt = 0.f;
#pragma unroll
            for (int h2 = 0; h2 < 8; ++h2) tt += red2[h2];
            out[b] = tt + opb[0];
        }
    } else {
        unsigned short oh = f2bf(o);
        size_t p = (size_t)b * HID + tid;
        outh[p] = oh;
        outl[p] = f2bf(o - bf2f(oh));
    }
}

extern "C" void kernel_launch(void* const* d_in, const int* in_sizes, int n_in,
                              void* d_out, int out_size, void* d_ws, size_t ws_size,
                              hipStream_t stream) {
    const float* V    = (const float*)d_in[0];
    const float* t    = (const float*)d_in[1];
    const float* ip_w = (const float*)d_in[2];
    const float* ip_b = (const float*)d_in[3];
    const float* op_w = (const float*)d_in[4];
    const float* op_b = (const float*)d_in[5];
    const float* s0_W = (const float*)d_in[6];
    const float* s0_b = (const float*)d_in[7];
    const float* s2_W = (const float*)d_in[9];
    const float* s2_b = (const float*)d_in[10];
    const float* m1_Wq = (const float*)d_in[12];
    const float* m1_Wk = (const float*)d_in[13];
    const float* m1_Wv = (const float*)d_in[14];
    const float* m1_bq = (const float*)d_in[15];
    const float* m1_bk = (const float*)d_in[16];
    const float* m1_bv = (const float*)d_in[17];
    const float* m1_igw = (const float*)d_in[18];
    const float* m1_igb = (const float*)d_in[19];
    const float* m1_lng = (const float*)d_in[22];
    const float* m1_lnb = (const float*)d_in[23];
    const float* m3_Wq = (const float*)d_in[24];
    const float* m3_Wk = (const float*)d_in[25];
    const float* m3_Wv = (const float*)d_in[26];
    const float* m3_bq = (const float*)d_in[27];
    const float* m3_bk = (const float*)d_in[28];
    const float* m3_bv = (const float*)d_in[29];
    const float* m3_igw = (const float*)d_in[30];
    const float* m3_igb = (const float*)d_in[31];
    const float* m3_lng = (const float*)d_in[34];
    const float* m3_lnb = (const float*)d_in[35];

    char* ws = (char*)d_ws;
    bf16* whi  = (bf16*)ws;                            // 3,670,016 elems
    bf16* wlo  = (bf16*)(ws + 7340032);
    bf16* hAhi = (bf16*)(ws + 14680064);               // [B][HID] each 2 MB
    bf16* hAlo = (bf16*)(ws + 16777216);
    bf16* hBhi = (bf16*)(ws + 18874368);
    bf16* hBlo = (bf16*)(ws + 20971520);
    float* gq0 = (float*)(ws + 23068672);              // [B][1536] f32 qkv

    CvtArgs ca;
    ca.src[0] = s0_W; ca.src[1] = s2_W;
    ca.src[2] = m1_Wq; ca.src[3] = m1_Wk; ca.src[4] = m1_Wv;
    ca.src[5] = m3_Wq; ca.src[6] = m3_Wk; ca.src[7] = m3_Wv;
    k_prep<<<4608, 256, 0, stream>>>(ca, (unsigned short*)whi, (unsigned short*)wlo,
                                     V, t, ip_w, ip_b,
                                     (unsigned short*)hAhi, (unsigned short*)hAlo);

    // layer 0: sLSTM fused GEMM+activation (s0 weights at offset 0)
    k_gemm_s<<<256, 256, 0, stream>>>(hAhi, hAlo, whi + 0, wlo + 0, s0_b,
                                      (unsigned short*)hBhi, (unsigned short*)hBlo);
    // layer 1: mLSTM (fused q|k|v GEMM, single C)
    k_gemm_m<<<192, 256, 0, stream>>>(hBhi, hBlo,
        whi + 2097152, whi + 2359296, whi + 2621440,
        wlo + 2097152, wlo + 2359296, wlo + 2621440, gq0);
    k_mlstm<<<BATCH, 512, 0, stream>>>(gq0, m1_bq, m1_bk, m1_bv, hBhi, hBlo,
                                       m1_igw, m1_igb, m1_lng, m1_lnb,
                                       (unsigned short*)hAhi, (unsigned short*)hAlo,
                                       nullptr, nullptr, nullptr);
    // layer 2: sLSTM fused (s2 weights at offset 1048576)
    k_gemm_s<<<256, 256, 0, stream>>>(hAhi, hAlo, whi + 1048576, wlo + 1048576, s2_b,
                                      (unsigned short*)hBhi, (unsigned short*)hBlo);
    // layer 3: mLSTM + fused output projection
    k_gemm_m<<<192, 256, 0, stream>>>(hBhi, hBlo,
        whi + 2883584, whi + 3145728, whi + 3407872,
        wlo + 2883584, wlo + 3145728, wlo + 3407872, gq0);
    k_mlstm<<<BATCH, 512, 0, stream>>>(gq0, m3_bq, m3_bk, m3_bv, hBhi, hBlo,
                                       m3_igw, m3_igb, m3_lng, m3_lnb,
                                       nullptr, nullptr,
                                       op_w, op_b, (float*)d_out);
}

// Round 11
// 136.631 us; speedup vs baseline: 1.0248x; 1.0248x over previous
//
#include <hip/hip_runtime.h>
#include <hip/hip_bf16.h>

#define HID 512
#define BATCH 2048

typedef __bf16 bf16x8 __attribute__((ext_vector_type(8)));
typedef float f32x4 __attribute__((ext_vector_type(4)));
typedef float f32x16 __attribute__((ext_vector_type(16)));
typedef __hip_bfloat16 bf16;

__device__ inline unsigned short f2bf(float x) {
    bf16 h = __float2bfloat16(x);
    return __builtin_bit_cast(unsigned short, h);
}
__device__ inline float bf2f(unsigned short u) {
    return __bfloat162float(__builtin_bit_cast(bf16, u));
}

__device__ inline void gload16(const void* g, void* l) {
    __builtin_amdgcn_global_load_lds((const __attribute__((address_space(1))) void*)g,
                                     (__attribute__((address_space(3))) void*)l, 16, 0, 0);
}

// ---------------- merged: weight fp32 -> hi/lo bf16 split  +  input projection ----------------
struct CvtArgs { const float* src[8]; };

__global__ void k_prep(CvtArgs a, unsigned short* __restrict__ hi, unsigned short* __restrict__ lo,
                       const float* __restrict__ V, const float* __restrict__ t,
                       const float* __restrict__ ipw, const float* __restrict__ ipb,
                       unsigned short* __restrict__ hhi, unsigned short* __restrict__ hlo) {
    const int bid = blockIdx.x;
    if (bid < 3584) {   // cvt part: 3,670,016 elems / 4
        int idx4 = (bid * 256 + threadIdx.x) << 2;
        int seg, off;
        if (idx4 < 2097152) { seg = idx4 >> 20; off = idx4 & 1048575; }
        else { int r = idx4 - 2097152; seg = 2 + (r >> 18); off = r & 262143; }
        f32x4 w = *(const f32x4*)(a.src[seg] + off);
        ushort4 h, l;
        h.x = f2bf(w[0]); h.y = f2bf(w[1]); h.z = f2bf(w[2]); h.w = f2bf(w[3]);
        l.x = f2bf(w[0] - bf2f(h.x)); l.y = f2bf(w[1] - bf2f(h.y));
        l.z = f2bf(w[2] - bf2f(h.z)); l.w = f2bf(w[3] - bf2f(h.w));
        *(ushort4*)(hi + idx4) = h;
        *(ushort4*)(lo + idx4) = l;
    } else {            // h0 part: B*HID/4 elems
        int idx = (bid - 3584) * 256 + threadIdx.x;
        int b = idx >> 7, j4 = (idx & 127) << 2;
        float vv = V[b], tt = t[b];
        f32x4 w0 = *(const f32x4*)(ipw + 2 * j4);
        f32x4 w1 = *(const f32x4*)(ipw + 2 * j4 + 4);
        f32x4 bb = *(const f32x4*)(ipb + j4);
        float x[4] = { w0[0] * vv + w0[1] * tt + bb[0], w0[2] * vv + w0[3] * tt + bb[1],
                       w1[0] * vv + w1[1] * tt + bb[2], w1[2] * vv + w1[3] * tt + bb[3] };
        ushort4 h, l;
        h.x = f2bf(x[0]); h.y = f2bf(x[1]); h.z = f2bf(x[2]); h.w = f2bf(x[3]);
        l.x = f2bf(x[0] - bf2f(h.x)); l.y = f2bf(x[1] - bf2f(h.y));
        l.z = f2bf(x[2] - bf2f(h.z)); l.w = f2bf(x[3] - bf2f(h.w));
        size_t o = (size_t)b * HID + j4;
        *(ushort4*)(hhi + o) = h;
        *(ushort4*)(hlo + o) = l;
    }
}

// ---------------- native-K split-bf16 GEMM, split-K=2, 4-deep counted-vmcnt pipeline ----------------
// C_kh[2048][1536] = Ah*Wh + Al*Wh + Ah*Wl over native K-half (256), no bias.
// Block tile 64m x 128n, 4 waves, wave tile 32m x 64n = 1x2 frags of mfma_f32_32x32x16_bf16, BK=16.
// Grid 768 = 8 XCD x 96 slots (2 k-halves x 4 m-tiles x 12 n-tiles per XCD): 3 blocks/CU,
// 12 waves/CU -> 3 waves/SIMD TLP on top of a 3-step-deep prefetch (vmcnt(6) steady state).
// LDS: 4 bufs x 12 chunks x 1KB = 48 KB. Chunk c: 0,1 = Ah m-frags; 2,3 = Al; 4-7 = Wh n-frags;
// 8-11 = Wl. Chunk: lane l <-> row (l&31), k = 8*(l>>5) .. +8.  Wave w stages chunks 3w..3w+2.
__global__ __launch_bounds__(256, 3) void k_gemm(
    const bf16* __restrict__ Ahi, const bf16* __restrict__ Alo,
    const bf16* __restrict__ Wh0, const bf16* __restrict__ Wh1, const bf16* __restrict__ Wh2,
    const bf16* __restrict__ Wl0, const bf16* __restrict__ Wl1, const bf16* __restrict__ Wl2,
    float* __restrict__ C0, float* __restrict__ C1)
{
    __shared__ __align__(16) bf16 lds[4][6144];   // 48 KB
    const int tid = threadIdx.x, w = tid >> 6, lane = tid & 63;

    const int bid = blockIdx.x;
    const int xcd = bid & 7, s = bid >> 3;         // slot 0..95
    const int kh = s >= 48;
    const int r  = s - 48 * kh;                    // 0..47
    const int m0 = (xcd * 4 + r / 12) * 64;        // XCD owns m rows [xcd*256, xcd*256+256)
    const int n0 = (r % 12) * 128;
    const int nseg = n0 >> 9, nloc = n0 & 511;
    const bf16* Wh = nseg == 0 ? Wh0 : (nseg == 1 ? Wh1 : Wh2);
    const bf16* Wl = nseg == 0 ? Wl0 : (nseg == 1 ? Wl1 : Wl2);
    const int kbase = kh * 256;

    const int rowk = lane & 31;
    const int kofs = (lane >> 5) << 3;
    auto src_of = [&](int c) -> const bf16* {
        const bf16* base; int row;
        if (c < 2)      { base = Ahi; row = m0 + (c << 5); }
        else if (c < 4) { base = Alo; row = m0 + ((c - 2) << 5); }
        else if (c < 8) { base = Wh;  row = nloc + ((c - 4) << 5); }
        else            { base = Wl;  row = nloc + ((c - 8) << 5); }
        return base + (size_t)(row + rowk) * HID + kbase + kofs;
    };
    const bf16* sp0 = src_of(3 * w);
    const bf16* sp1 = src_of(3 * w + 1);
    const bf16* sp2 = src_of(3 * w + 2);
    bf16* const d0 = &lds[0][0] + 3 * w * 512 + (lane << 3);

    auto STAGE = [&](int t) {
        bf16* d = d0 + (t & 3) * 6144;
        const int ko = t << 4;
        gload16(sp0 + ko, d);
        gload16(sp1 + ko, d + 512);
        gload16(sp2 + ko, d + 1024);
    };

    const int la = lane << 3;
    const int ca  = ((w >> 1)) << 9;
    const int cal = (2 + (w >> 1)) << 9;
    const int cw0 = (4 + ((w & 1) << 1)) << 9;
    const int cw1 = (5 + ((w & 1) << 1)) << 9;
    const int cl0 = (8 + ((w & 1) << 1)) << 9;
    const int cl1 = (9 + ((w & 1) << 1)) << 9;
    f32x16 acc0 = {}, acc1 = {};

    STAGE(0); STAGE(1); STAGE(2);
    for (int t = 0; t < 16; ++t) {
        // wait own STAGE(t) done; stages t+1..t+3 (<=6 loads after retire) stay in flight.
        if (t <= 13)
            asm volatile("s_waitcnt vmcnt(6) lgkmcnt(0)\n\ts_barrier" ::: "memory");
        else if (t == 14)
            asm volatile("s_waitcnt vmcnt(3) lgkmcnt(0)\n\ts_barrier" ::: "memory");
        else
            asm volatile("s_waitcnt vmcnt(0) lgkmcnt(0)\n\ts_barrier" ::: "memory");
        if (t < 13) STAGE(t + 3);   // writes buf (t-1)&3: all reads drained via lgkmcnt+barrier
        const bf16* lb = &lds[t & 3][0];
        bf16x8 ah  = *(const bf16x8*)(lb + ca  + la);
        bf16x8 al  = *(const bf16x8*)(lb + cal + la);
        bf16x8 wh0v = *(const bf16x8*)(lb + cw0 + la);
        bf16x8 wh1v = *(const bf16x8*)(lb + cw1 + la);
        bf16x8 wl0v = *(const bf16x8*)(lb + cl0 + la);
        bf16x8 wl1v = *(const bf16x8*)(lb + cl1 + la);
        acc0 = __builtin_amdgcn_mfma_f32_32x32x16_bf16(ah, wh0v, acc0, 0, 0, 0);
        acc1 = __builtin_amdgcn_mfma_f32_32x32x16_bf16(ah, wh1v, acc1, 0, 0, 0);
        acc0 = __builtin_amdgcn_mfma_f32_32x32x16_bf16(al, wh0v, acc0, 0, 0, 0);
        acc1 = __builtin_amdgcn_mfma_f32_32x32x16_bf16(al, wh1v, acc1, 0, 0, 0);
        acc0 = __builtin_amdgcn_mfma_f32_32x32x16_bf16(ah, wl0v, acc0, 0, 0, 0);
        acc1 = __builtin_amdgcn_mfma_f32_32x32x16_bf16(ah, wl1v, acc1, 0, 0, 0);
    }

    // epilogue: D layout col = lane&31, row = (rr&3) + 8*(rr>>2) + 4*(lane>>5)
    float* Cp = kh ? C1 : C0;
    const int colb = n0 + ((w & 1) << 6) + (lane & 31);
    const int rbase = m0 + ((w >> 1) << 5) + ((lane >> 5) << 2);
#pragma unroll
    for (int f = 0; f < 2; ++f) {
        const f32x16& ac = f ? acc1 : acc0;
        const int col = colb + (f << 5);
#pragma unroll
        for (int rr = 0; rr < 16; ++rr) {
            int row = rbase + (rr & 3) + ((rr >> 2) << 3);
            Cp[(size_t)row * 1536 + col] = ac[rr];
        }
    }
}

// ---------------- sLSTM activation: sum partials + bias, h = sigm(o)*tanh(exp(i)*tanh(g)) ----------------
__global__ void k_slstm_act(const float* __restrict__ g0, const float* __restrict__ g1,
                            const float* __restrict__ bp,
                            unsigned short* __restrict__ hhi, unsigned short* __restrict__ hlo) {
    int idx = blockIdx.x * blockDim.x + threadIdx.x;   // B*HID/4
    int b = idx >> 7, j4 = (idx & 127) << 2;
    const float* r0 = g0 + (size_t)b * 1536 + j4;
    const float* r1 = g1 + (size_t)b * 1536 + j4;
    f32x4 gi = *(const f32x4*)r0 + *(const f32x4*)r1 + *(const f32x4*)(bp + j4);
    f32x4 gg = *(const f32x4*)(r0 + 512) + *(const f32x4*)(r1 + 512) + *(const f32x4*)(bp + 1024 + j4);
    f32x4 go = *(const f32x4*)(r0 + 1024) + *(const f32x4*)(r1 + 1024) + *(const f32x4*)(bp + 1536 + j4);
    ushort4 h, l;
    float x[4];
#pragma unroll
    for (int u = 0; u < 4; ++u)
        x[u] = tanhf(expf(gi[u]) * tanhf(gg[u])) / (1.f + expf(-go[u]));
    h.x = f2bf(x[0]); h.y = f2bf(x[1]); h.z = f2bf(x[2]); h.w = f2bf(x[3]);
    l.x = f2bf(x[0] - bf2f(h.x)); l.y = f2bf(x[1] - bf2f(h.y));
    l.z = f2bf(x[2] - bf2f(h.z)); l.w = f2bf(x[3] - bf2f(h.w));
    size_t o = (size_t)b * HID + j4;
    *(ushort4*)(hhi + o) = h;
    *(ushort4*)(hlo + o) = l;
}

// ---------------- mLSTM head math + layernorm (+optional fused final projection) ----------------
__global__ __launch_bounds__(512) void k_mlstm(
    const float* __restrict__ g0, const float* __restrict__ g1,
    const float* __restrict__ bq, const float* __restrict__ bk, const float* __restrict__ bv,
    const bf16* __restrict__ hinh, const bf16* __restrict__ hinl,
    const float* __restrict__ igw, const float* __restrict__ igb,
    const float* __restrict__ lng, const float* __restrict__ lnb,
    unsigned short* __restrict__ outh, unsigned short* __restrict__ outl,
    const float* __restrict__ opw, const float* __restrict__ opb, float* __restrict__ out)
{
    int b = blockIdx.x;
    int tid = threadIdx.x, head = tid >> 6, lane = tid & 63;

    const bf16*  hh = hinh + (size_t)b * HID;
    const bf16*  hl = hinl + (size_t)b * HID;
    const float* wrow = igw + head * HID;
    float s = 0.f;
#pragma unroll
    for (int k = 0; k < 8; ++k) {
        int p = lane + 64 * k;
        s += wrow[p] * (__bfloat162float(hh[p]) + __bfloat162float(hl[p]));
    }
#pragma unroll
    for (int off = 32; off; off >>= 1) s += __shfl_xor(s, off);
    float ig = expf(s + igb[head]);

    const float* r0 = g0 + (size_t)b * 1536;
    const float* r1 = g1 + (size_t)b * 1536;
    float q  = r0[tid] + r1[tid] + bq[tid];
    float kk = r0[512 + tid] + r1[512 + tid] + bk[tid];
    float v  = r0[1024 + tid] + r1[1024 + tid] + bv[tid];
    float kq = kk * q, vq = v * q;
#pragma unroll
    for (int off = 32; off; off >>= 1) { kq += __shfl_xor(kq, off); vq += __shfl_xor(vq, off); }
    float den = ig * (vq + 1.0f) + 1e-6f;
    float hv  = v * (ig * kq) / den;

    __shared__ float red[16];
    __shared__ float red2[8];
    float s1 = hv, s2 = hv * hv;
#pragma unroll
    for (int off = 32; off; off >>= 1) { s1 += __shfl_xor(s1, off); s2 += __shfl_xor(s2, off); }
    if (lane == 0) { red[head] = s1; red[8 + head] = s2; }
    __syncthreads();
    float t1 = 0.f, t2 = 0.f;
#pragma unroll
    for (int h2 = 0; h2 < 8; ++h2) { t1 += red[h2]; t2 += red[8 + h2]; }
    float mu  = t1 * (1.f / 512.f);
    float var = t2 * (1.f / 512.f) - mu * mu;
    float o = (hv - mu) * rsqrtf(var + 1e-5f) * lng[tid] + lnb[tid];

    if (out) {   // fused final projection (layer 3)
        float po = o * opw[tid];
#pragma unroll
        for (int off = 32; off; off >>= 1) po += __shfl_xor(po, off);
        if (lane == 0) red2[head] = po;
        __syncthreads();
        if (tid == 0) {
            float tt = 0.f;
#pragma unroll
            for (int h2 = 0; h2 < 8; ++h2) tt += red2[h2];
            out[b] = tt + opb[0];
        }
    } else {
        unsigned short oh = f2bf(o);
        size_t p = (size_t)b * HID + tid;
        outh[p] = oh;
        outl[p] = f2bf(o - bf2f(oh));
    }
}

extern "C" void kernel_launch(void* const* d_in, const int* in_sizes, int n_in,
                              void* d_out, int out_size, void* d_ws, size_t ws_size,
                              hipStream_t stream) {
    const float* V    = (const float*)d_in[0];
    const float* t    = (const float*)d_in[1];
    const float* ip_w = (const float*)d_in[2];
    const float* ip_b = (const float*)d_in[3];
    const float* op_w = (const float*)d_in[4];
    const float* op_b = (const float*)d_in[5];
    const float* s0_W = (const float*)d_in[6];
    const float* s0_b = (const float*)d_in[7];
    const float* s2_W = (const float*)d_in[9];
    const float* s2_b = (const float*)d_in[10];
    const float* m1_Wq = (const float*)d_in[12];
    const float* m1_Wk = (const float*)d_in[13];
    const float* m1_Wv = (const float*)d_in[14];
    const float* m1_bq = (const float*)d_in[15];
    const float* m1_bk = (const float*)d_in[16];
    const float* m1_bv = (const float*)d_in[17];
    const float* m1_igw = (const float*)d_in[18];
    const float* m1_igb = (const float*)d_in[19];
    const float* m1_lng = (const float*)d_in[22];
    const float* m1_lnb = (const float*)d_in[23];
    const float* m3_Wq = (const float*)d_in[24];
    const float* m3_Wk = (const float*)d_in[25];
    const float* m3_Wv = (const float*)d_in[26];
    const float* m3_bq = (const float*)d_in[27];
    const float* m3_bk = (const float*)d_in[28];
    const float* m3_bv = (const float*)d_in[29];
    const float* m3_igw = (const float*)d_in[30];
    const float* m3_igb = (const float*)d_in[31];
    const float* m3_lng = (const float*)d_in[34];
    const float* m3_lnb = (const float*)d_in[35];

    char* ws = (char*)d_ws;
    bf16* whi  = (bf16*)ws;                            // 3,670,016 elems
    bf16* wlo  = (bf16*)(ws + 7340032);
    bf16* hAhi = (bf16*)(ws + 14680064);               // [B][HID] each 2 MB
    bf16* hAlo = (bf16*)(ws + 16777216);
    bf16* hBhi = (bf16*)(ws + 18874368);
    bf16* hBlo = (bf16*)(ws + 20971520);
    float* gq0 = (float*)(ws + 23068672);              // [B][1536] f32 partial (khalf 0)
    float* gq1 = (float*)(ws + 23068672 + 12582912);   // [B][1536] f32 partial (khalf 1)

    CvtArgs ca;
    ca.src[0] = s0_W; ca.src[1] = s2_W;
    ca.src[2] = m1_Wq; ca.src[3] = m1_Wk; ca.src[4] = m1_Wv;
    ca.src[5] = m3_Wq; ca.src[6] = m3_Wk; ca.src[7] = m3_Wv;
    k_prep<<<4608, 256, 0, stream>>>(ca, (unsigned short*)whi, (unsigned short*)wlo,
                                     V, t, ip_w, ip_b,
                                     (unsigned short*)hAhi, (unsigned short*)hAlo);

    // layer 0: sLSTM (W rows: i=0-511, g=1024-1535, o=1536-2047)
    k_gemm<<<768, 256, 0, stream>>>(hAhi, hAlo,
        whi + 0, whi + 524288, whi + 786432,
        wlo + 0, wlo + 524288, wlo + 786432, gq0, gq1);
    k_slstm_act<<<1024, 256, 0, stream>>>(gq0, gq1, s0_b, (unsigned short*)hBhi, (unsigned short*)hBlo);
    // layer 1: mLSTM (fused q|k|v)
    k_gemm<<<768, 256, 0, stream>>>(hBhi, hBlo,
        whi + 2097152, whi + 2359296, whi + 2621440,
        wlo + 2097152, wlo + 2359296, wlo + 2621440, gq0, gq1);
    k_mlstm<<<BATCH, 512, 0, stream>>>(gq0, gq1, m1_bq, m1_bk, m1_bv, hBhi, hBlo,
                                       m1_igw, m1_igb, m1_lng, m1_lnb,
                                       (unsigned short*)hAhi, (unsigned short*)hAlo,
                                       nullptr, nullptr, nullptr);
    // layer 2: sLSTM
    k_gemm<<<768, 256, 0, stream>>>(hAhi, hAlo,
        whi + 1048576, whi + 1572864, whi + 1835008,
        wlo + 1048576, wlo + 1572864, wlo + 1835008, gq0, gq1);
    k_slstm_act<<<1024, 256, 0, stream>>>(gq0, gq1, s2_b, (unsigned short*)hBhi, (unsigned short*)hBlo);
    // layer 3: mLSTM + fused output projection
    k_gemm<<<768, 256, 0, stream>>>(hBhi, hBlo,
        whi + 2883584, whi + 3145728, whi + 3407872,
        wlo + 2883584, wlo + 3145728, wlo + 3407872, gq0, gq1);
    k_mlstm<<<BATCH, 512, 0, stream>>>(gq0, gq1, m3_bq, m3_bk, m3_bv, hBhi, hBlo,
                                       m3_igw, m3_igb, m3_lng, m3_lnb,
                                       nullptr, nullptr,
                                       op_w, op_b, (float*)d_out);
}

// Round 12
// 122.049 us; speedup vs baseline: 1.1473x; 1.1195x over previous
//
#include <hip/hip_runtime.h>
#include <hip/hip_bf16.h>

#define HID 512
#define BATCH 2048

typedef __bf16 bf16x8 __attribute__((ext_vector_type(8)));
typedef float f32x4 __attribute__((ext_vector_type(4)));
typedef float f32x16 __attribute__((ext_vector_type(16)));
typedef __hip_bfloat16 bf16;

__device__ inline unsigned short f2bf(float x) {
    bf16 h = __float2bfloat16(x);
    return __builtin_bit_cast(unsigned short, h);
}
__device__ inline float bf2f(unsigned short u) {
    return __bfloat162float(__builtin_bit_cast(bf16, u));
}

__device__ inline void gload16(const void* g, void* l) {
    __builtin_amdgcn_global_load_lds((const __attribute__((address_space(1))) void*)g,
                                     (__attribute__((address_space(3))) void*)l, 16, 0, 0);
}

// ---------------- merged: weight fp32 -> hi/lo bf16 split  +  input projection ----------------
struct CvtArgs { const float* src[8]; };

__global__ void k_prep(CvtArgs a, unsigned short* __restrict__ hi, unsigned short* __restrict__ lo,
                       const float* __restrict__ V, const float* __restrict__ t,
                       const float* __restrict__ ipw, const float* __restrict__ ipb,
                       unsigned short* __restrict__ hhi, unsigned short* __restrict__ hlo) {
    const int bid = blockIdx.x;
    if (bid < 3584) {   // cvt part: 3,670,016 elems / 4
        int idx4 = (bid * 256 + threadIdx.x) << 2;
        int seg, off;
        if (idx4 < 2097152) { seg = idx4 >> 20; off = idx4 & 1048575; }
        else { int r = idx4 - 2097152; seg = 2 + (r >> 18); off = r & 262143; }
        f32x4 w = *(const f32x4*)(a.src[seg] + off);
        ushort4 h, l;
        h.x = f2bf(w[0]); h.y = f2bf(w[1]); h.z = f2bf(w[2]); h.w = f2bf(w[3]);
        l.x = f2bf(w[0] - bf2f(h.x)); l.y = f2bf(w[1] - bf2f(h.y));
        l.z = f2bf(w[2] - bf2f(h.z)); l.w = f2bf(w[3] - bf2f(h.w));
        *(ushort4*)(hi + idx4) = h;
        *(ushort4*)(lo + idx4) = l;
    } else {            // h0 part: B*HID/4 elems
        int idx = (bid - 3584) * 256 + threadIdx.x;
        int b = idx >> 7, j4 = (idx & 127) << 2;
        float vv = V[b], tt = t[b];
        f32x4 w0 = *(const f32x4*)(ipw + 2 * j4);
        f32x4 w1 = *(const f32x4*)(ipw + 2 * j4 + 4);
        f32x4 bb = *(const f32x4*)(ipb + j4);
        float x[4] = { w0[0] * vv + w0[1] * tt + bb[0], w0[2] * vv + w0[3] * tt + bb[1],
                       w1[0] * vv + w1[1] * tt + bb[2], w1[2] * vv + w1[3] * tt + bb[3] };
        ushort4 h, l;
        h.x = f2bf(x[0]); h.y = f2bf(x[1]); h.z = f2bf(x[2]); h.w = f2bf(x[3]);
        l.x = f2bf(x[0] - bf2f(h.x)); l.y = f2bf(x[1] - bf2f(h.y));
        l.z = f2bf(x[2] - bf2f(h.z)); l.w = f2bf(x[3] - bf2f(h.w));
        size_t o = (size_t)b * HID + j4;
        *(ushort4*)(hhi + o) = h;
        *(ushort4*)(hlo + o) = l;
    }
}

// ---------------- native-K split-bf16 GEMM (NO split-K, deep 32-step K-loop) ----------------
// C[2048][1536] = Ah*Wh + Al*Wh + Ah*Wl over K=512.  Block 128x128, 4 waves, BK=16, 32 steps.
// Proven ~MFMA-floor in round 10.  3-buffer counted-vmcnt pipeline, XCD m-slab ownership.
// LDS buffer = 16 chunks of 1KB; chunk c: matrix m=c>>2 (0=Ah,1=Al,2=Wh,3=Wl), rowblock rb=c&3.
// Chunk: lane l <-> row (l&31), k = 8*(l>>5) .. +8.  Wave w stages matrix w (4 gloads/step).
__global__ __launch_bounds__(256, 2) void k_gemm(
    const bf16* __restrict__ Ahi, const bf16* __restrict__ Alo,
    const bf16* __restrict__ Wh0, const bf16* __restrict__ Wh1, const bf16* __restrict__ Wh2,
    const bf16* __restrict__ Wl0, const bf16* __restrict__ Wl1, const bf16* __restrict__ Wl2,
    float* __restrict__ C)
{
    __shared__ __align__(16) bf16 lds[3][8192];   // 48 KB
    const int tid = threadIdx.x, w = tid >> 6, lane = tid & 63;

    const int bid = blockIdx.x;                   // 192 blocks: 8 XCD x 24 slots
    const int xcd = bid & 7, slot = bid >> 3;     // slot 0..23
    const int m0 = (xcd * 2 + slot / 12) * 128;   // XCD owns m rows [xcd*256, +256)
    const int n0 = (slot % 12) * 128;
    const int nseg = n0 >> 9, nloc = n0 & 511;
    const bf16* Wh = nseg == 0 ? Wh0 : (nseg == 1 ? Wh1 : Wh2);
    const bf16* Wl = nseg == 0 ? Wl0 : (nseg == 1 ? Wl1 : Wl2);

    const bf16* msrc = (w == 0) ? Ahi : (w == 1) ? Alo : (w == 2) ? Wh : Wl;
    const int rowbase = (w < 2) ? m0 : nloc;
    const size_t srow = (size_t)(rowbase + (lane & 31)) * HID + ((lane >> 5) << 3);

    auto STAGE = [&](int t) {
        bf16* db = &lds[t % 3][0] + (w << 11) + (lane << 3);
        const bf16* gp = msrc + srow + (t << 4);
#pragma unroll
        for (int p = 0; p < 4; ++p)
            gload16(gp + (size_t)(p << 5) * HID, db + (p << 9));
    };

    const int wm = w >> 1, wn = w & 1;
    const int la = lane << 3;
    f32x16 acc00 = {}, acc01 = {}, acc10 = {}, acc11 = {};

    STAGE(0);
    STAGE(1);
    for (int t = 0; t < 32; ++t) {
        if (t < 31)
            asm volatile("s_waitcnt vmcnt(4) lgkmcnt(0)\n\ts_barrier" ::: "memory");
        else
            asm volatile("s_waitcnt vmcnt(0) lgkmcnt(0)\n\ts_barrier" ::: "memory");
        if (t < 30) STAGE(t + 2);
        const bf16* lb = &lds[t % 3][0];
        bf16x8 ah0 = *(const bf16x8*)(lb + ((2 * wm    ) << 9) + la);
        bf16x8 ah1 = *(const bf16x8*)(lb + ((2 * wm + 1) << 9) + la);
        bf16x8 al0 = *(const bf16x8*)(lb + ((4 + 2 * wm    ) << 9) + la);
        bf16x8 al1 = *(const bf16x8*)(lb + ((4 + 2 * wm + 1) << 9) + la);
        bf16x8 wh0 = *(const bf16x8*)(lb + ((8 + 2 * wn    ) << 9) + la);
        bf16x8 wh1 = *(const bf16x8*)(lb + ((8 + 2 * wn + 1) << 9) + la);
        bf16x8 wl0 = *(const bf16x8*)(lb + ((12 + 2 * wn    ) << 9) + la);
        bf16x8 wl1 = *(const bf16x8*)(lb + ((12 + 2 * wn + 1) << 9) + la);
        acc00 = __builtin_amdgcn_mfma_f32_32x32x16_bf16(ah0, wh0, acc00, 0, 0, 0);
        acc01 = __builtin_amdgcn_mfma_f32_32x32x16_bf16(ah0, wh1, acc01, 0, 0, 0);
        acc10 = __builtin_amdgcn_mfma_f32_32x32x16_bf16(ah1, wh0, acc10, 0, 0, 0);
        acc11 = __builtin_amdgcn_mfma_f32_32x32x16_bf16(ah1, wh1, acc11, 0, 0, 0);
        acc00 = __builtin_amdgcn_mfma_f32_32x32x16_bf16(al0, wh0, acc00, 0, 0, 0);
        acc01 = __builtin_amdgcn_mfma_f32_32x32x16_bf16(al0, wh1, acc01, 0, 0, 0);
        acc10 = __builtin_amdgcn_mfma_f32_32x32x16_bf16(al1, wh0, acc10, 0, 0, 0);
        acc11 = __builtin_amdgcn_mfma_f32_32x32x16_bf16(al1, wh1, acc11, 0, 0, 0);
        acc00 = __builtin_amdgcn_mfma_f32_32x32x16_bf16(ah0, wl0, acc00, 0, 0, 0);
        acc01 = __builtin_amdgcn_mfma_f32_32x32x16_bf16(ah0, wl1, acc01, 0, 0, 0);
        acc10 = __builtin_amdgcn_mfma_f32_32x32x16_bf16(ah1, wl0, acc10, 0, 0, 0);
        acc11 = __builtin_amdgcn_mfma_f32_32x32x16_bf16(ah1, wl1, acc11, 0, 0, 0);
    }

    // epilogue: D layout col = lane&31, row = (rr&3) + 8*(rr>>2) + 4*(lane>>5)
    const f32x16* accs[2][2] = { { &acc00, &acc01 }, { &acc10, &acc11 } };
#pragma unroll
    for (int fi = 0; fi < 2; ++fi)
#pragma unroll
        for (int fj = 0; fj < 2; ++fj) {
            const f32x16& ac = *accs[fi][fj];
            const int col = n0 + ((2 * wn + fj) << 5) + (lane & 31);
            const int rbase = m0 + ((2 * wm + fi) << 5) + ((lane >> 5) << 2);
#pragma unroll
            for (int rr = 0; rr < 16; ++rr) {
                int row = rbase + (rr & 3) + ((rr >> 2) << 3);
                C[(size_t)row * 1536 + col] = ac[rr];
            }
        }
}

// ---------------- sLSTM activation: + bias, h = sigm(o)*tanh(exp(i)*tanh(g)) ----------------
__global__ void k_slstm_act(const float* __restrict__ g, const float* __restrict__ bp,
                            unsigned short* __restrict__ hhi, unsigned short* __restrict__ hlo) {
    int idx = blockIdx.x * blockDim.x + threadIdx.x;   // B*HID/4
    int b = idx >> 7, j4 = (idx & 127) << 2;
    const float* r0 = g + (size_t)b * 1536 + j4;
    f32x4 gi = *(const f32x4*)r0 + *(const f32x4*)(bp + j4);
    f32x4 gg = *(const f32x4*)(r0 + 512) + *(const f32x4*)(bp + 1024 + j4);
    f32x4 go = *(const f32x4*)(r0 + 1024) + *(const f32x4*)(bp + 1536 + j4);
    ushort4 h, l;
    float x[4];
#pragma unroll
    for (int u = 0; u < 4; ++u)
        x[u] = tanhf(expf(gi[u]) * tanhf(gg[u])) / (1.f + expf(-go[u]));
    h.x = f2bf(x[0]); h.y = f2bf(x[1]); h.z = f2bf(x[2]); h.w = f2bf(x[3]);
    l.x = f2bf(x[0] - bf2f(h.x)); l.y = f2bf(x[1] - bf2f(h.y));
    l.z = f2bf(x[2] - bf2f(h.z)); l.w = f2bf(x[3] - bf2f(h.w));
    size_t o = (size_t)b * HID + j4;
    *(ushort4*)(hhi + o) = h;
    *(ushort4*)(hlo + o) = l;
}

// ---------------- mLSTM head math + layernorm (+optional fused final projection) ----------------
__global__ __launch_bounds__(512) void k_mlstm(
    const float* __restrict__ g0,
    const float* __restrict__ bq, const float* __restrict__ bk, const float* __restrict__ bv,
    const bf16* __restrict__ hinh, const bf16* __restrict__ hinl,
    const float* __restrict__ igw, const float* __restrict__ igb,
    const float* __restrict__ lng, const float* __restrict__ lnb,
    unsigned short* __restrict__ outh, unsigned short* __restrict__ outl,
    const float* __restrict__ opw, const float* __restrict__ opb, float* __restrict__ out)
{
    int b = blockIdx.x;
    int tid = threadIdx.x, head = tid >> 6, lane = tid & 63;

    const bf16*  hh = hinh + (size_t)b * HID;
    const bf16*  hl = hinl + (size_t)b * HID;
    const float* wrow = igw + head * HID;
    float s = 0.f;
#pragma unroll
    for (int k = 0; k < 8; ++k) {
        int p = lane + 64 * k;
        s += wrow[p] * (__bfloat162float(hh[p]) + __bfloat162float(hl[p]));
    }
#pragma unroll
    for (int off = 32; off; off >>= 1) s += __shfl_xor(s, off);
    float ig = expf(s + igb[head]);

    const float* r0 = g0 + (size_t)b * 1536;
    float q  = r0[tid] + bq[tid];
    float kk = r0[512 + tid] + bk[tid];
    float v  = r0[1024 + tid] + bv[tid];
    float kq = kk * q, vq = v * q;
#pragma unroll
    for (int off = 32; off; off >>= 1) { kq += __shfl_xor(kq, off); vq += __shfl_xor(vq, off); }
    float den = ig * (vq + 1.0f) + 1e-6f;
    float hv  = v * (ig * kq) / den;

    __shared__ float red[16];
    __shared__ float red2[8];
    float s1 = hv, s2 = hv * hv;
#pragma unroll
    for (int off = 32; off; off >>= 1) { s1 += __shfl_xor(s1, off); s2 += __shfl_xor(s2, off); }
    if (lane == 0) { red[head] = s1; red[8 + head] = s2; }
    __syncthreads();
    float t1 = 0.f, t2 = 0.f;
#pragma unroll
    for (int h2 = 0; h2 < 8; ++h2) { t1 += red[h2]; t2 += red[8 + h2]; }
    float mu  = t1 * (1.f / 512.f);
    float var = t2 * (1.f / 512.f) - mu * mu;
    float o = (hv - mu) * rsqrtf(var + 1e-5f) * lng[tid] + lnb[tid];

    if (out) {   // fused final projection (layer 3)
        float po = o * opw[tid];
#pragma unroll
        for (int off = 32; off; off >>= 1) po += __shfl_xor(po, off);
        if (lane == 0) red2[head] = po;
        __syncthreads();
        if (tid == 0) {
            float tt = 0.f;
#pragma unroll
            for (int h2 = 0; h2 < 8; ++h2) tt += red2[h2];
            out[b] = tt + opb[0];
        }
    } else {
        unsigned short oh = f2bf(o);
        size_t p = (size_t)b * HID + tid;
        outh[p] = oh;
        outl[p] = f2bf(o - bf2f(oh));
    }
}

extern "C" void kernel_launch(void* const* d_in, const int* in_sizes, int n_in,
                              void* d_out, int out_size, void* d_ws, size_t ws_size,
                              hipStream_t stream) {
    const float* V    = (const float*)d_in[0];
    const float* t    = (const float*)d_in[1];
    const float* ip_w = (const float*)d_in[2];
    const float* ip_b = (const float*)d_in[3];
    const float* op_w = (const float*)d_in[4];
    const float* op_b = (const float*)d_in[5];
    const float* s0_W = (const float*)d_in[6];
    const float* s0_b = (const float*)d_in[7];
    const float* s2_W = (const float*)d_in[9];
    const float* s2_b = (const float*)d_in[10];
    const float* m1_Wq = (const float*)d_in[12];
    const float* m1_Wk = (const float*)d_in[13];
    const float* m1_Wv = (const float*)d_in[14];
    const float* m1_bq = (const float*)d_in[15];
    const float* m1_bk = (const float*)d_in[16];
    const float* m1_bv = (const float*)d_in[17];
    const float* m1_igw = (const float*)d_in[18];
    const float* m1_igb = (const float*)d_in[19];
    const float* m1_lng = (const float*)d_in[22];
    const float* m1_lnb = (const float*)d_in[23];
    const float* m3_Wq = (const float*)d_in[24];
    const float* m3_Wk = (const float*)d_in[25];
    const float* m3_Wv = (const float*)d_in[26];
    const float* m3_bq = (const float*)d_in[27];
    const float* m3_bk = (const float*)d_in[28];
    const float* m3_bv = (const float*)d_in[29];
    const float* m3_igw = (const float*)d_in[30];
    const float* m3_igb = (const float*)d_in[31];
    const float* m3_lng = (const float*)d_in[34];
    const float* m3_lnb = (const float*)d_in[35];

    char* ws = (char*)d_ws;
    bf16* whi  = (bf16*)ws;                            // 3,670,016 elems
    bf16* wlo  = (bf16*)(ws + 7340032);
    bf16* hAhi = (bf16*)(ws + 14680064);               // [B][HID] each 2 MB
    bf16* hAlo = (bf16*)(ws + 16777216);
    bf16* hBhi = (bf16*)(ws + 18874368);
    bf16* hBlo = (bf16*)(ws + 20971520);
    float* gq0 = (float*)(ws + 23068672);              // [B][1536] f32 gates/qkv

    CvtArgs ca;
    ca.src[0] = s0_W; ca.src[1] = s2_W;
    ca.src[2] = m1_Wq; ca.src[3] = m1_Wk; ca.src[4] = m1_Wv;
    ca.src[5] = m3_Wq; ca.src[6] = m3_Wk; ca.src[7] = m3_Wv;
    k_prep<<<4608, 256, 0, stream>>>(ca, (unsigned short*)whi, (unsigned short*)wlo,
                                     V, t, ip_w, ip_b,
                                     (unsigned short*)hAhi, (unsigned short*)hAlo);

    // layer 0: sLSTM (W rows: i=0-511, g=1024-1535, o=1536-2047)
    k_gemm<<<192, 256, 0, stream>>>(hAhi, hAlo,
        whi + 0, whi + 524288, whi + 786432,
        wlo + 0, wlo + 524288, wlo + 786432, gq0);
    k_slstm_act<<<1024, 256, 0, stream>>>(gq0, s0_b, (unsigned short*)hBhi, (unsigned short*)hBlo);
    // layer 1: mLSTM (fused q|k|v)
    k_gemm<<<192, 256, 0, stream>>>(hBhi, hBlo,
        whi + 2097152, whi + 2359296, whi + 2621440,
        wlo + 2097152, wlo + 2359296, wlo + 2621440, gq0);
    k_mlstm<<<BATCH, 512, 0, stream>>>(gq0, m1_bq, m1_bk, m1_bv, hBhi, hBlo,
                                       m1_igw, m1_igb, m1_lng, m1_lnb,
                                       (unsigned short*)hAhi, (unsigned short*)hAlo,
                                       nullptr, nullptr, nullptr);
    // layer 2: sLSTM
    k_gemm<<<192, 256, 0, stream>>>(hAhi, hAlo,
        whi + 1048576, whi + 1572864, whi + 1835008,
        wlo + 1048576, wlo + 1572864, wlo + 1835008, gq0);
    k_slstm_act<<<1024, 256, 0, stream>>>(gq0, s2_b, (unsigned short*)hBhi, (unsigned short*)hBlo);
    // layer 3: mLSTM + fused output projection
    k_gemm<<<192, 256, 0, stream>>>(hBhi, hBlo,
        whi + 2883584, whi + 3145728, whi + 3407872,
        wlo + 2883584, wlo + 3145728, wlo + 3407872, gq0);
    k_mlstm<<<BATCH, 512, 0, stream>>>(gq0, m3_bq, m3_bk, m3_bv, hBhi, hBlo,
                                       m3_igw, m3_igb, m3_lng, m3_lnb,
                                       nullptr, nullptr,
                                       op_w, op_b, (float*)d_out);
}